// Round 5
// baseline (2424.760 us; speedup 1.0000x reference)
//
#include <hip/hip_runtime.h>
#include <cfloat>
#include <climits>

#define TPB 256

// ---------------------------------------------------------------------------
// Numerics contract (rounds 3-4 PASSED): every matmul output is a
// k-sequential single-accumulator fp32 fmaf chain (k ascending), bias via
// __fadd_rn (encoder), norms via numpy pairwise order,
// d = fl(fl(nl+ne) - fl(2*dot)), argmin strict-< with first-index ties.
// Round-5: vq -> acc[8][8] with B streamed from L2 (kills the 2x LDS-BW
// bottleneck); enc/dec -> acc[2][8] (2x load ILP). Chains unchanged.
// ---------------------------------------------------------------------------

// ============================ prep: W -> WT ================================
__global__ __launch_bounds__(TPB) void wt_kernel(
    const float* __restrict__ W1, const float* __restrict__ W2,
    const float* __restrict__ W3, const float* __restrict__ U1,
    const float* __restrict__ U2, const float* __restrict__ Umu,
    const float* __restrict__ Ulv, float* __restrict__ wt) {
  __shared__ float sB[64 * 68];
  const int b = blockIdx.x;
  const float* src; int R, C, lt; float* dst;
  if (b < 8)       { src = W1;  R = 256; C = 128; dst = wt;          lt = b; }
  else if (b < 16) { src = W2;  R = 128; C = 256; dst = wt + 32768;  lt = b - 8; }
  else if (b < 18) { src = W3;  R = 64;  C = 128; dst = wt + 65536;  lt = b - 16; }
  else if (b < 20) { src = U1;  R = 128; C = 64;  dst = wt + 73728;  lt = b - 18; }
  else if (b < 28) { src = U2;  R = 256; C = 128; dst = wt + 81920;  lt = b - 20; }
  else if (b < 36) { src = Umu; R = 128; C = 256; dst = wt + 114688; lt = b - 28; }
  else             { src = Ulv; R = 128; C = 256; dst = wt + 147456; lt = b - 36; }
  const int tiles_r = R >> 6;
  const int r0 = (lt % tiles_r) << 6, c0 = (lt / tiles_r) << 6;
  const int t = threadIdx.x;
  for (int v = t; v < 1024; v += TPB) {
    const int c4 = v & 15, r = v >> 4;
    const float4 w =
        *reinterpret_cast<const float4*>(src + (size_t)(r0 + r) * C + c0 + 4 * c4);
    *reinterpret_cast<float4*>(&sB[r * 68 + 4 * c4]) = w;
  }
  __syncthreads();
  for (int v = t; v < 1024; v += TPB) {
    const int r4 = v & 15, c = v >> 4;
    float4 o;
    o.x = sB[(4 * r4 + 0) * 68 + c];
    o.y = sB[(4 * r4 + 1) * 68 + c];
    o.z = sB[(4 * r4 + 2) * 68 + c];
    o.w = sB[(4 * r4 + 3) * 68 + c];
    *reinterpret_cast<float4*>(dst + (size_t)(c0 + c) * R + r0 + 4 * r4) = o;
  }
}

// ====================== prep: emb -> embT, + En ============================
__global__ __launch_bounds__(TPB) void embt_kernel(const float* __restrict__ emb,
                                                   float* __restrict__ embT,
                                                   float* __restrict__ En) {
  __shared__ float sB[64 * 68];  // [code][d]
  const int c0 = blockIdx.x * 64;
  const int t = threadIdx.x;
  for (int v = t; v < 1024; v += TPB) {
    const int d4 = v & 15, r = v >> 4;
    const float4 e =
        *reinterpret_cast<const float4*>(emb + (size_t)(c0 + r) * 64 + 4 * d4);
    *reinterpret_cast<float4*>(&sB[r * 68 + 4 * d4]) = e;
  }
  __syncthreads();
  if (t < 64) {  // numpy pairwise ||e||^2
    const float* row = &sB[t * 68];
    float q[8];
#pragma unroll
    for (int j = 0; j < 8; ++j) q[j] = __fmul_rn(row[j], row[j]);
#pragma unroll
    for (int m = 1; m < 8; ++m)
#pragma unroll
      for (int j = 0; j < 8; ++j) {
        const float v = row[m * 8 + j];
        q[j] = __fadd_rn(q[j], __fmul_rn(v, v));
      }
    En[c0 + t] = __fadd_rn(
        __fadd_rn(__fadd_rn(q[0], q[1]), __fadd_rn(q[2], q[3])),
        __fadd_rn(__fadd_rn(q[4], q[5]), __fadd_rn(q[6], q[7])));
  }
  for (int v = t; v < 1024; v += TPB) {
    const int r4 = v & 15, d = v >> 4;
    float4 o;
    o.x = sB[(4 * r4 + 0) * 68 + d];
    o.y = sB[(4 * r4 + 1) * 68 + d];
    o.z = sB[(4 * r4 + 2) * 68 + d];
    o.w = sB[(4 * r4 + 3) * 68 + d];
    *reinterpret_cast<float4*>(embT + (size_t)d * 8192 + c0 + 4 * r4) = o;
  }
}

// ========================= fused encoder (32 rows) =========================
// acc[2][8]: two 64-col chunks per pass -> 2 independent weight-load streams.
__global__ __launch_bounds__(TPB) void enc_fused(
    const float* __restrict__ x, const float* __restrict__ WT1,
    const float* __restrict__ WT2, const float* __restrict__ WT3,
    const float* __restrict__ b1, const float* __restrict__ b2,
    const float* __restrict__ b3, float* __restrict__ lat) {
  __shared__ float sX[128 * 36];
  __shared__ float sH1[256 * 36];
  __shared__ float sH2[128 * 36];
  const int t = threadIdx.x;
  const int tx4 = (t & 15) * 4, ty2 = (t >> 4) * 2;
  const int m0 = blockIdx.x * 32;

  for (int v = t; v < 1024; v += TPB) {
    const int k4 = v & 31, r = v >> 5;
    const float4 xv =
        *reinterpret_cast<const float4*>(x + (size_t)(m0 + r) * 128 + 4 * k4);
    float* dst = &sX[(4 * k4) * 36 + r];
    dst[0] = xv.x; dst[36] = xv.y; dst[72] = xv.z; dst[108] = xv.w;
  }
  __syncthreads();

  // L1: K=128, N=256 -> two passes of 128 cols (acc[2][8])
  for (int cp = 0; cp < 2; ++cp) {
    float acc[2][8] = {};
#pragma unroll 8
    for (int k = 0; k < 128; ++k) {
      const float2 a = *reinterpret_cast<const float2*>(&sX[k * 36 + ty2]);
      const float* wr = WT1 + (size_t)k * 256 + cp * 128;
      const float4 b0 = *reinterpret_cast<const float4*>(wr + tx4);
      const float4 b1v = *reinterpret_cast<const float4*>(wr + 64 + tx4);
      const float av[2] = {a.x, a.y};
      const float bv[8] = {b0.x, b0.y, b0.z, b0.w, b1v.x, b1v.y, b1v.z, b1v.w};
#pragma unroll
      for (int i = 0; i < 2; ++i)
#pragma unroll
        for (int j = 0; j < 8; ++j) acc[i][j] = fmaf(av[i], bv[j], acc[i][j]);
    }
#pragma unroll
    for (int j = 0; j < 8; ++j) {
      const int col = cp * 128 + (j >> 2) * 64 + tx4 + (j & 3);
      const float bj = b1[col];
#pragma unroll
      for (int i = 0; i < 2; ++i) {
        const float h = __fadd_rn(acc[i][j], bj);
        sH1[col * 36 + ty2 + i] = h > 0.f ? h : 0.f;
      }
    }
  }
  __syncthreads();

  // L2: K=256, N=128 -> one pass (acc[2][8])
  {
    float acc[2][8] = {};
#pragma unroll 8
    for (int k = 0; k < 256; ++k) {
      const float2 a = *reinterpret_cast<const float2*>(&sH1[k * 36 + ty2]);
      const float* wr = WT2 + (size_t)k * 128;
      const float4 b0 = *reinterpret_cast<const float4*>(wr + tx4);
      const float4 b1v = *reinterpret_cast<const float4*>(wr + 64 + tx4);
      const float av[2] = {a.x, a.y};
      const float bv[8] = {b0.x, b0.y, b0.z, b0.w, b1v.x, b1v.y, b1v.z, b1v.w};
#pragma unroll
      for (int i = 0; i < 2; ++i)
#pragma unroll
        for (int j = 0; j < 8; ++j) acc[i][j] = fmaf(av[i], bv[j], acc[i][j]);
    }
#pragma unroll
    for (int j = 0; j < 8; ++j) {
      const int col = (j >> 2) * 64 + tx4 + (j & 3);
      const float bj = b2[col];
#pragma unroll
      for (int i = 0; i < 2; ++i) {
        const float h = __fadd_rn(acc[i][j], bj);
        sH2[col * 36 + ty2 + i] = h > 0.f ? h : 0.f;
      }
    }
  }
  __syncthreads();

  // L3: K=128, N=64 -> lat
  {
    float acc[2][4] = {};
#pragma unroll 8
    for (int k = 0; k < 128; ++k) {
      const float2 a = *reinterpret_cast<const float2*>(&sH2[k * 36 + ty2]);
      const float4 bb =
          *reinterpret_cast<const float4*>(WT3 + (size_t)k * 64 + tx4);
      const float av[2] = {a.x, a.y};
      const float bv[4] = {bb.x, bb.y, bb.z, bb.w};
#pragma unroll
      for (int i = 0; i < 2; ++i)
#pragma unroll
        for (int j = 0; j < 4; ++j) acc[i][j] = fmaf(av[i], bv[j], acc[i][j]);
    }
#pragma unroll
    for (int i = 0; i < 2; ++i) {
      float4 o;
      o.x = __fadd_rn(acc[i][0], b3[tx4 + 0]);
      o.y = __fadd_rn(acc[i][1], b3[tx4 + 1]);
      o.z = __fadd_rn(acc[i][2], b3[tx4 + 2]);
      o.w = __fadd_rn(acc[i][3], b3[tx4 + 3]);
      *reinterpret_cast<float4*>(lat + (size_t)(m0 + ty2 + i) * 64 + tx4) = o;
    }
  }
}

// ================================ VQ =======================================
// 64 rows/block, acc[8][8]: 256 thr = 8 row-groups (ty=t>>5) x 32 col-groups
// (tx=t&31). A (lat) from LDS broadcast (2 b128, 2-4 distinct addr/wave);
// B (emb) streamed directly from embT: 1 KB contiguous per wave per d,
// ~2 MB hot working set in L1/L2. No barriers in the K-loop. d_k =
// fl(fl(nl+ne) - fl(2*dot)) with the same k-sequential chain; argmin
// first-index via strict < and lexicographic 32-lane shuffle merge.
__global__ __launch_bounds__(TPB) void vq_kernel(
    const float* __restrict__ lat, const float* __restrict__ embT,
    const float* __restrict__ En, int* __restrict__ inds,
    float* __restrict__ lossp, float* __restrict__ oh) {
  __shared__ float sL[64 * 68];  // lat_t [64d][68r]
  __shared__ float snl[64];
  __shared__ int ridx[64];
  __shared__ float lacc;
  const int t = threadIdx.x;
  const int tx = t & 31, ty = t >> 5;  // col-group, row-group
  const int r0 = ty * 8;               // rows r0..r0+7
  const int m0 = blockIdx.x * 64;

  for (int v = t; v < 1024; v += TPB) {
    const int r = v >> 4, d4 = v & 15;
    const float4 lv =
        *reinterpret_cast<const float4*>(lat + (size_t)(m0 + r) * 64 + 4 * d4);
    float* dst = &sL[(4 * d4) * 68 + r];
    dst[0] = lv.x; dst[68] = lv.y; dst[136] = lv.z; dst[204] = lv.w;
  }
  if (t == 0) lacc = 0.f;
  __syncthreads();
  if (t < 64) {  // numpy pairwise ||lat_r||^2
    float q[8];
#pragma unroll
    for (int j = 0; j < 8; ++j) {
      const float v = sL[j * 68 + t];
      q[j] = __fmul_rn(v, v);
    }
#pragma unroll
    for (int m = 1; m < 8; ++m)
#pragma unroll
      for (int j = 0; j < 8; ++j) {
        const float v = sL[(m * 8 + j) * 68 + t];
        q[j] = __fadd_rn(q[j], __fmul_rn(v, v));
      }
    snl[t] = __fadd_rn(
        __fadd_rn(__fadd_rn(q[0], q[1]), __fadd_rn(q[2], q[3])),
        __fadd_rn(__fadd_rn(q[4], q[5]), __fadd_rn(q[6], q[7])));
  }
  __syncthreads();
  float nl[8];
#pragma unroll
  for (int i = 0; i < 8; ++i) nl[i] = snl[r0 + i];

  float v1[8];
  int i1[8];
#pragma unroll
  for (int i = 0; i < 8; ++i) { v1[i] = FLT_MAX; i1[i] = INT_MAX; }

  for (int ch = 0; ch < 32; ++ch) {  // 8192 codes, 256-col chunks
    const int c0 = ch * 256;
    const int cbase = c0 + tx * 8;  // this thread's 8 cols
    float acc[8][8] = {};
#pragma unroll 2
    for (int d = 0; d < 64; ++d) {  // k-sequential fma chain
      const float* er = embT + (size_t)d * 8192 + cbase;
      const float4 b0 = *reinterpret_cast<const float4*>(er);
      const float4 b1v = *reinterpret_cast<const float4*>(er + 4);
      const float4 a0 = *reinterpret_cast<const float4*>(&sL[d * 68 + r0]);
      const float4 a1 = *reinterpret_cast<const float4*>(&sL[d * 68 + r0 + 4]);
      const float av[8] = {a0.x, a0.y, a0.z, a0.w, a1.x, a1.y, a1.z, a1.w};
      const float bv[8] = {b0.x, b0.y, b0.z, b0.w, b1v.x, b1v.y, b1v.z, b1v.w};
#pragma unroll
      for (int i = 0; i < 8; ++i)
#pragma unroll
        for (int j = 0; j < 8; ++j) acc[i][j] = fmaf(av[i], bv[j], acc[i][j]);
    }
#pragma unroll
    for (int j = 0; j < 8; ++j) {
      const float Ec = En[cbase + j];
      const int c = cbase + j;
#pragma unroll
      for (int i = 0; i < 8; ++i) {
        const float t1 = __fadd_rn(nl[i], Ec);
        const float s = __fsub_rn(t1, __fmul_rn(2.0f, acc[i][j]));
        if (s < v1[i]) { v1[i] = s; i1[i] = c; }
      }
    }
    // spread one_hot zeros for this chunk (64 rows x 64 float4-cols)
    const float4 z = make_float4(0.f, 0.f, 0.f, 0.f);
    for (int v = t; v < 4096; v += TPB) {
      const int r = v >> 6, c4 = v & 63;
      *reinterpret_cast<float4*>(oh + (size_t)(m0 + r) * 8192 + c0 + 4 * c4) =
          z;
    }
  }

  // merge across the 32 col-group lanes (within-wave), first-index ties
#pragma unroll
  for (int m = 16; m >= 1; m >>= 1) {
#pragma unroll
    for (int i = 0; i < 8; ++i) {
      const float ov = __shfl_xor(v1[i], m);
      const int oi = __shfl_xor(i1[i], m);
      if (ov < v1[i] || (ov == v1[i] && oi < i1[i])) {
        v1[i] = ov; i1[i] = oi;
      }
    }
  }
  if (tx == 0) {
    float ls = 0.f;
#pragma unroll
    for (int i = 0; i < 8; ++i) {
      ridx[r0 + i] = i1[i];
      inds[m0 + r0 + i] = i1[i];
      ls += v1[i];  // d_min == ||q-lat||^2
    }
    atomicAdd(&lacc, ls);
  }
  __syncthreads();
  if (t == 0) lossp[blockIdx.x] = lacc;

  // patch ones: owner thread of (r, c4-slot) wrote the zero earlier (same
  // thread -> same-address program order, no fence needed)
  for (int v = t; v < 4096; v += TPB) {
    const int r = v >> 6, c4 = v & 63;
    const int ind = ridx[r];
    const int g4 = ind >> 2;  // global float4 col
    if ((g4 & 63) == c4) {
      float4 o = make_float4(0.f, 0.f, 0.f, 0.f);
      reinterpret_cast<float*>(&o)[ind & 3] = 1.f;
      *reinterpret_cast<float4*>(oh + (size_t)(m0 + r) * 8192 + 4 * g4) = o;
    }
  }
}

// ========================= fused decoder (32 rows) =========================
__global__ __launch_bounds__(TPB) void dec_fused(
    const float* __restrict__ emb, const int* __restrict__ inds,
    const float* __restrict__ WT1, const float* __restrict__ b1,
    const float* __restrict__ WT2, const float* __restrict__ b2,
    const float* __restrict__ WTmu, const float* __restrict__ bmu,
    const float* __restrict__ WTlv, const float* __restrict__ blv,
    float* __restrict__ xh, float* __restrict__ xv) {
  __shared__ float sQ[64 * 36];
  __shared__ float sG1[128 * 36];
  __shared__ float sG2[256 * 36];
  const int t = threadIdx.x;
  const int tx4 = (t & 15) * 4, ty2 = (t >> 4) * 2;
  const int m0 = blockIdx.x * 32;

  for (int v = t; v < 512; v += TPB) {  // gather q transposed
    const int k4 = v & 15, r = v >> 4;
    const int id = inds[m0 + r];
    const float4 e =
        *reinterpret_cast<const float4*>(emb + (size_t)id * 64 + 4 * k4);
    float* dst = &sQ[(4 * k4) * 36 + r];
    dst[0] = e.x; dst[36] = e.y; dst[72] = e.z; dst[108] = e.w;
  }
  __syncthreads();

  // L1: K=64, N=128 (acc[2][8])
  {
    float acc[2][8] = {};
#pragma unroll 8
    for (int k = 0; k < 64; ++k) {
      const float2 a = *reinterpret_cast<const float2*>(&sQ[k * 36 + ty2]);
      const float* wr = WT1 + (size_t)k * 128;
      const float4 b0 = *reinterpret_cast<const float4*>(wr + tx4);
      const float4 b1v = *reinterpret_cast<const float4*>(wr + 64 + tx4);
      const float av[2] = {a.x, a.y};
      const float bv[8] = {b0.x, b0.y, b0.z, b0.w, b1v.x, b1v.y, b1v.z, b1v.w};
#pragma unroll
      for (int i = 0; i < 2; ++i)
#pragma unroll
        for (int j = 0; j < 8; ++j) acc[i][j] = fmaf(av[i], bv[j], acc[i][j]);
    }
#pragma unroll
    for (int j = 0; j < 8; ++j) {
      const int col = (j >> 2) * 64 + tx4 + (j & 3);
      const float bj = b1[col];
#pragma unroll
      for (int i = 0; i < 2; ++i) {
        const float h = acc[i][j] + bj;
        sG1[col * 36 + ty2 + i] = h > 0.f ? h : 0.f;
      }
    }
  }
  __syncthreads();

  // L2: K=128, N=256 -> two passes (acc[2][8])
  for (int cp = 0; cp < 2; ++cp) {
    float acc[2][8] = {};
#pragma unroll 8
    for (int k = 0; k < 128; ++k) {
      const float2 a = *reinterpret_cast<const float2*>(&sG1[k * 36 + ty2]);
      const float* wr = WT2 + (size_t)k * 256 + cp * 128;
      const float4 b0 = *reinterpret_cast<const float4*>(wr + tx4);
      const float4 b1v = *reinterpret_cast<const float4*>(wr + 64 + tx4);
      const float av[2] = {a.x, a.y};
      const float bv[8] = {b0.x, b0.y, b0.z, b0.w, b1v.x, b1v.y, b1v.z, b1v.w};
#pragma unroll
      for (int i = 0; i < 2; ++i)
#pragma unroll
        for (int j = 0; j < 8; ++j) acc[i][j] = fmaf(av[i], bv[j], acc[i][j]);
    }
#pragma unroll
    for (int j = 0; j < 8; ++j) {
      const int col = cp * 128 + (j >> 2) * 64 + tx4 + (j & 3);
      const float bj = b2[col];
#pragma unroll
      for (int i = 0; i < 2; ++i) {
        const float h = acc[i][j] + bj;
        sG2[col * 36 + ty2 + i] = h > 0.f ? h : 0.f;
      }
    }
  }
  __syncthreads();

  // heads: K=256, N=128 each (acc[2][8])
  for (int head = 0; head < 2; ++head) {
    const float* WT = head ? WTlv : WTmu;
    const float* bb_ = head ? blv : bmu;
    float* o = head ? xv : xh;
    float acc[2][8] = {};
#pragma unroll 8
    for (int k = 0; k < 256; ++k) {
      const float2 a = *reinterpret_cast<const float2*>(&sG2[k * 36 + ty2]);
      const float* wr = WT + (size_t)k * 128;
      const float4 b0 = *reinterpret_cast<const float4*>(wr + tx4);
      const float4 b1v = *reinterpret_cast<const float4*>(wr + 64 + tx4);
      const float av[2] = {a.x, a.y};
      const float bv[8] = {b0.x, b0.y, b0.z, b0.w, b1v.x, b1v.y, b1v.z, b1v.w};
#pragma unroll
      for (int i = 0; i < 2; ++i)
#pragma unroll
        for (int j = 0; j < 8; ++j) acc[i][j] = fmaf(av[i], bv[j], acc[i][j]);
    }
#pragma unroll
    for (int i = 0; i < 2; ++i) {
      float4 o0, o1;
      o0.x = acc[i][0] + bb_[tx4 + 0];
      o0.y = acc[i][1] + bb_[tx4 + 1];
      o0.z = acc[i][2] + bb_[tx4 + 2];
      o0.w = acc[i][3] + bb_[tx4 + 3];
      o1.x = acc[i][4] + bb_[64 + tx4 + 0];
      o1.y = acc[i][5] + bb_[64 + tx4 + 1];
      o1.z = acc[i][6] + bb_[64 + tx4 + 2];
      o1.w = acc[i][7] + bb_[64 + tx4 + 3];
      float* orow = o + (size_t)(m0 + ty2 + i) * 128;
      *reinterpret_cast<float4*>(orow + tx4) = o0;
      *reinterpret_cast<float4*>(orow + 64 + tx4) = o1;
    }
  }
}

// vq_loss = 2.25 * sum(d_min) / (N*LAT)
__global__ void fin_kernel(const float* __restrict__ lossp,
                           float* __restrict__ outp) {
  const int t = threadIdx.x;  // 64
  double s = 0.0;
  for (int i = t; i < 512; i += 64) s += (double)lossp[i];
#pragma unroll
  for (int m = 32; m >= 1; m >>= 1) s += __shfl_xor(s, m);
  if (t == 0) *outp = (float)(2.25 * s / (32768.0 * 64.0));
}

// ---------------------------------------------------------------------------
extern "C" void kernel_launch(void* const* d_in, const int* in_sizes, int n_in,
                              void* d_out, int out_size, void* d_ws,
                              size_t ws_size, hipStream_t stream) {
  const float* x = (const float*)d_in[0];
  const float* eW1 = (const float*)d_in[1];
  const float* eb1 = (const float*)d_in[2];
  const float* eW2 = (const float*)d_in[3];
  const float* eb2 = (const float*)d_in[4];
  const float* eW3 = (const float*)d_in[5];
  const float* eb3 = (const float*)d_in[6];
  const float* emb = (const float*)d_in[7];
  const float* dW1 = (const float*)d_in[8];
  const float* db1 = (const float*)d_in[9];
  const float* dW2 = (const float*)d_in[10];
  const float* db2 = (const float*)d_in[11];
  const float* dWmu = (const float*)d_in[12];
  const float* dbmu = (const float*)d_in[13];
  const float* dWlv = (const float*)d_in[14];
  const float* dblv = (const float*)d_in[15];

  float* out = (float*)d_out;
  float* xhat = out;                 // [32768,128]
  float* xvar = out + 4194304;       // [32768,128]
  float* oh = out + 8388608;         // [32768,8192]
  float* lossout = out + 276824064;  // scalar

  // ws layout (floats)
  float* lat = (float*)d_ws;             // 2,097,152
  float* En = lat + 2097152;             // 8,192
  float* lossp = En + 8192;              // 512
  int* inds = (int*)(lossp + 512);       // 32,768
  float* embT = (float*)(inds + 32768);  // 524,288  [64][8192]
  float* wt = embT + 524288;             // WT pool
  float* wt1 = wt;                       // [128][256]
  float* wt2 = wt + 32768;               // [256][128]
  float* wt3 = wt + 65536;               // [128][64]
  float* uwt1 = wt + 73728;              // [64][128]
  float* uwt2 = wt + 81920;              // [128][256]
  float* uwtmu = wt + 114688;            // [256][128]
  float* uwtlv = wt + 147456;            // [256][128]

  wt_kernel<<<44, TPB, 0, stream>>>(eW1, eW2, eW3, dW1, dW2, dWmu, dWlv, wt);
  embt_kernel<<<128, TPB, 0, stream>>>(emb, embT, En);
  enc_fused<<<1024, TPB, 0, stream>>>(x, wt1, wt2, wt3, eb1, eb2, eb3, lat);
  vq_kernel<<<512, TPB, 0, stream>>>(lat, embT, En, inds, lossp, oh);
  dec_fused<<<1024, TPB, 0, stream>>>(emb, inds, uwt1, db1, uwt2, db2, uwtmu,
                                      dbmu, uwtlv, dblv, xhat, xvar);
  fin_kernel<<<1, 64, 0, stream>>>(lossp, lossout);
}

// Round 6
// 1816.710 us; speedup vs baseline: 1.3347x; 1.3347x over previous
//
#include <hip/hip_runtime.h>
#include <cfloat>
#include <climits>

#define TPB 256

// ---------------------------------------------------------------------------
// Numerics contract (rounds 3-5 PASSED): every matmul output is a
// k-sequential single-accumulator fp32 fmaf chain (k ascending), bias via
// __fadd_rn (encoder), norms via numpy pairwise order,
// d = fl(fl(nl+ne) - fl(2*dot)), argmin strict-< with first-index ties.
// Round-6: vq goes back to LDS-staged B (round-4 style; round-5's per-d
// global B was L2-latency-bound at 27% VALUBusy) with an 8x4 acc tile:
// 32 FMA per b128 B-read, broadcast A-reads, 51.6 KB LDS -> 3 blocks/CU.
// ---------------------------------------------------------------------------

// ============================ prep: W -> WT ================================
__global__ __launch_bounds__(TPB) void wt_kernel(
    const float* __restrict__ W1, const float* __restrict__ W2,
    const float* __restrict__ W3, const float* __restrict__ U1,
    const float* __restrict__ U2, const float* __restrict__ Umu,
    const float* __restrict__ Ulv, float* __restrict__ wt) {
  __shared__ float sB[64 * 68];
  const int b = blockIdx.x;
  const float* src; int R, C, lt; float* dst;
  if (b < 8)       { src = W1;  R = 256; C = 128; dst = wt;          lt = b; }
  else if (b < 16) { src = W2;  R = 128; C = 256; dst = wt + 32768;  lt = b - 8; }
  else if (b < 18) { src = W3;  R = 64;  C = 128; dst = wt + 65536;  lt = b - 16; }
  else if (b < 20) { src = U1;  R = 128; C = 64;  dst = wt + 73728;  lt = b - 18; }
  else if (b < 28) { src = U2;  R = 256; C = 128; dst = wt + 81920;  lt = b - 20; }
  else if (b < 36) { src = Umu; R = 128; C = 256; dst = wt + 114688; lt = b - 28; }
  else             { src = Ulv; R = 128; C = 256; dst = wt + 147456; lt = b - 36; }
  const int tiles_r = R >> 6;
  const int r0 = (lt % tiles_r) << 6, c0 = (lt / tiles_r) << 6;
  const int t = threadIdx.x;
  for (int v = t; v < 1024; v += TPB) {
    const int c4 = v & 15, r = v >> 4;
    const float4 w =
        *reinterpret_cast<const float4*>(src + (size_t)(r0 + r) * C + c0 + 4 * c4);
    *reinterpret_cast<float4*>(&sB[r * 68 + 4 * c4]) = w;
  }
  __syncthreads();
  for (int v = t; v < 1024; v += TPB) {
    const int r4 = v & 15, c = v >> 4;
    float4 o;
    o.x = sB[(4 * r4 + 0) * 68 + c];
    o.y = sB[(4 * r4 + 1) * 68 + c];
    o.z = sB[(4 * r4 + 2) * 68 + c];
    o.w = sB[(4 * r4 + 3) * 68 + c];
    *reinterpret_cast<float4*>(dst + (size_t)(c0 + c) * R + r0 + 4 * r4) = o;
  }
}

// ====================== prep: emb -> embT, + En ============================
__global__ __launch_bounds__(TPB) void embt_kernel(const float* __restrict__ emb,
                                                   float* __restrict__ embT,
                                                   float* __restrict__ En) {
  __shared__ float sB[64 * 68];  // [code][d]
  const int c0 = blockIdx.x * 64;
  const int t = threadIdx.x;
  for (int v = t; v < 1024; v += TPB) {
    const int d4 = v & 15, r = v >> 4;
    const float4 e =
        *reinterpret_cast<const float4*>(emb + (size_t)(c0 + r) * 64 + 4 * d4);
    *reinterpret_cast<float4*>(&sB[r * 68 + 4 * d4]) = e;
  }
  __syncthreads();
  if (t < 64) {  // numpy pairwise ||e||^2
    const float* row = &sB[t * 68];
    float q[8];
#pragma unroll
    for (int j = 0; j < 8; ++j) q[j] = __fmul_rn(row[j], row[j]);
#pragma unroll
    for (int m = 1; m < 8; ++m)
#pragma unroll
      for (int j = 0; j < 8; ++j) {
        const float v = row[m * 8 + j];
        q[j] = __fadd_rn(q[j], __fmul_rn(v, v));
      }
    En[c0 + t] = __fadd_rn(
        __fadd_rn(__fadd_rn(q[0], q[1]), __fadd_rn(q[2], q[3])),
        __fadd_rn(__fadd_rn(q[4], q[5]), __fadd_rn(q[6], q[7])));
  }
  for (int v = t; v < 1024; v += TPB) {
    const int r4 = v & 15, d = v >> 4;
    float4 o;
    o.x = sB[(4 * r4 + 0) * 68 + d];
    o.y = sB[(4 * r4 + 1) * 68 + d];
    o.z = sB[(4 * r4 + 2) * 68 + d];
    o.w = sB[(4 * r4 + 3) * 68 + d];
    *reinterpret_cast<float4*>(embT + (size_t)d * 8192 + c0 + 4 * r4) = o;
  }
}

// ========================= fused encoder (32 rows) =========================
__global__ __launch_bounds__(TPB) void enc_fused(
    const float* __restrict__ x, const float* __restrict__ WT1,
    const float* __restrict__ WT2, const float* __restrict__ WT3,
    const float* __restrict__ b1, const float* __restrict__ b2,
    const float* __restrict__ b3, float* __restrict__ lat) {
  __shared__ float sX[128 * 36];
  __shared__ float sH1[256 * 36];
  __shared__ float sH2[128 * 36];
  const int t = threadIdx.x;
  const int tx4 = (t & 15) * 4, ty2 = (t >> 4) * 2;
  const int m0 = blockIdx.x * 32;

  for (int v = t; v < 1024; v += TPB) {
    const int k4 = v & 31, r = v >> 5;
    const float4 xv =
        *reinterpret_cast<const float4*>(x + (size_t)(m0 + r) * 128 + 4 * k4);
    float* dst = &sX[(4 * k4) * 36 + r];
    dst[0] = xv.x; dst[36] = xv.y; dst[72] = xv.z; dst[108] = xv.w;
  }
  __syncthreads();

  // L1: K=128, N=256 -> two passes of 128 cols (acc[2][8])
  for (int cp = 0; cp < 2; ++cp) {
    float acc[2][8] = {};
#pragma unroll 8
    for (int k = 0; k < 128; ++k) {
      const float2 a = *reinterpret_cast<const float2*>(&sX[k * 36 + ty2]);
      const float* wr = WT1 + (size_t)k * 256 + cp * 128;
      const float4 b0 = *reinterpret_cast<const float4*>(wr + tx4);
      const float4 b1v = *reinterpret_cast<const float4*>(wr + 64 + tx4);
      const float av[2] = {a.x, a.y};
      const float bv[8] = {b0.x, b0.y, b0.z, b0.w, b1v.x, b1v.y, b1v.z, b1v.w};
#pragma unroll
      for (int i = 0; i < 2; ++i)
#pragma unroll
        for (int j = 0; j < 8; ++j) acc[i][j] = fmaf(av[i], bv[j], acc[i][j]);
    }
#pragma unroll
    for (int j = 0; j < 8; ++j) {
      const int col = cp * 128 + (j >> 2) * 64 + tx4 + (j & 3);
      const float bj = b1[col];
#pragma unroll
      for (int i = 0; i < 2; ++i) {
        const float h = __fadd_rn(acc[i][j], bj);
        sH1[col * 36 + ty2 + i] = h > 0.f ? h : 0.f;
      }
    }
  }
  __syncthreads();

  // L2: K=256, N=128 -> one pass (acc[2][8])
  {
    float acc[2][8] = {};
#pragma unroll 8
    for (int k = 0; k < 256; ++k) {
      const float2 a = *reinterpret_cast<const float2*>(&sH1[k * 36 + ty2]);
      const float* wr = WT2 + (size_t)k * 128;
      const float4 b0 = *reinterpret_cast<const float4*>(wr + tx4);
      const float4 b1v = *reinterpret_cast<const float4*>(wr + 64 + tx4);
      const float av[2] = {a.x, a.y};
      const float bv[8] = {b0.x, b0.y, b0.z, b0.w, b1v.x, b1v.y, b1v.z, b1v.w};
#pragma unroll
      for (int i = 0; i < 2; ++i)
#pragma unroll
        for (int j = 0; j < 8; ++j) acc[i][j] = fmaf(av[i], bv[j], acc[i][j]);
    }
#pragma unroll
    for (int j = 0; j < 8; ++j) {
      const int col = (j >> 2) * 64 + tx4 + (j & 3);
      const float bj = b2[col];
#pragma unroll
      for (int i = 0; i < 2; ++i) {
        const float h = __fadd_rn(acc[i][j], bj);
        sH2[col * 36 + ty2 + i] = h > 0.f ? h : 0.f;
      }
    }
  }
  __syncthreads();

  // L3: K=128, N=64 -> lat
  {
    float acc[2][4] = {};
#pragma unroll 8
    for (int k = 0; k < 128; ++k) {
      const float2 a = *reinterpret_cast<const float2*>(&sH2[k * 36 + ty2]);
      const float4 bb =
          *reinterpret_cast<const float4*>(WT3 + (size_t)k * 64 + tx4);
      const float av[2] = {a.x, a.y};
      const float bv[4] = {bb.x, bb.y, bb.z, bb.w};
#pragma unroll
      for (int i = 0; i < 2; ++i)
#pragma unroll
        for (int j = 0; j < 4; ++j) acc[i][j] = fmaf(av[i], bv[j], acc[i][j]);
    }
#pragma unroll
    for (int i = 0; i < 2; ++i) {
      float4 o;
      o.x = __fadd_rn(acc[i][0], b3[tx4 + 0]);
      o.y = __fadd_rn(acc[i][1], b3[tx4 + 1]);
      o.z = __fadd_rn(acc[i][2], b3[tx4 + 2]);
      o.w = __fadd_rn(acc[i][3], b3[tx4 + 3]);
      *reinterpret_cast<float4*>(lat + (size_t)(m0 + ty2 + i) * 64 + tx4) = o;
    }
  }
}

// ================================ VQ =======================================
// 64 rows/block, 128-col chunks staged into LDS (conflict-free b128 writes
// from embT; latency paid once per chunk, not per d). 256 thr = 8 row-groups
// (ty=t>>5, 8 rows) x 32 col-groups (tx=t&31, 4 cols); acc[8][4]:
// per d = 2 broadcast b128 A-reads + 1 distinct b128 B-read per 32 FMAs.
// LDS 51.6 KB -> 3 blocks/CU. Numerics chain identical to rounds 3-5.
__global__ __launch_bounds__(TPB) void vq_kernel(
    const float* __restrict__ lat, const float* __restrict__ embT,
    const float* __restrict__ En, int* __restrict__ inds,
    float* __restrict__ lossp, float* __restrict__ oh) {
  __shared__ float sL[64 * 68];   // lat_t [64d][68r]
  __shared__ float sE[64 * 132];  // emb_t chunk [64d][132c]
  __shared__ float sEn[128];
  __shared__ float snl[64];
  __shared__ int ridx[64];
  __shared__ float lacc;
  const int t = threadIdx.x;
  const int tx = t & 31, ty = t >> 5;  // col-group (4 cols), row-group (8 rows)
  const int r0 = ty * 8;
  const int tx4 = tx * 4;
  const int m0 = blockIdx.x * 64;

  for (int v = t; v < 1024; v += TPB) {
    const int r = v >> 4, d4 = v & 15;
    const float4 lv =
        *reinterpret_cast<const float4*>(lat + (size_t)(m0 + r) * 64 + 4 * d4);
    float* dst = &sL[(4 * d4) * 68 + r];
    dst[0] = lv.x; dst[68] = lv.y; dst[136] = lv.z; dst[204] = lv.w;
  }
  if (t == 0) lacc = 0.f;
  __syncthreads();
  if (t < 64) {  // numpy pairwise ||lat_r||^2
    float q[8];
#pragma unroll
    for (int j = 0; j < 8; ++j) {
      const float v = sL[j * 68 + t];
      q[j] = __fmul_rn(v, v);
    }
#pragma unroll
    for (int m = 1; m < 8; ++m)
#pragma unroll
      for (int j = 0; j < 8; ++j) {
        const float v = sL[(m * 8 + j) * 68 + t];
        q[j] = __fadd_rn(q[j], __fmul_rn(v, v));
      }
    snl[t] = __fadd_rn(
        __fadd_rn(__fadd_rn(q[0], q[1]), __fadd_rn(q[2], q[3])),
        __fadd_rn(__fadd_rn(q[4], q[5]), __fadd_rn(q[6], q[7])));
  }
  __syncthreads();
  float nl[8];
#pragma unroll
  for (int i = 0; i < 8; ++i) nl[i] = snl[r0 + i];

  float v1[8];
  int i1[8];
#pragma unroll
  for (int i = 0; i < 8; ++i) { v1[i] = FLT_MAX; i1[i] = INT_MAX; }

  for (int ch = 0; ch < 64; ++ch) {  // 8192 codes, 128-col chunks
    const int c0 = ch * 128;
    __syncthreads();
    for (int v = t; v < 2048; v += TPB) {  // stage sE: coalesced, conflict-free
      const int cl = v & 31, d = v >> 5;
      const float4 e = *reinterpret_cast<const float4*>(
          embT + (size_t)d * 8192 + c0 + 4 * cl);
      *reinterpret_cast<float4*>(&sE[d * 132 + 4 * cl]) = e;
    }
    if (t < 128) sEn[t] = En[c0 + t];
    __syncthreads();

    float acc[8][4] = {};
#pragma unroll 4
    for (int d = 0; d < 64; ++d) {  // k-sequential fma chain
      const float4 a0 = *reinterpret_cast<const float4*>(&sL[d * 68 + r0]);
      const float4 a1 = *reinterpret_cast<const float4*>(&sL[d * 68 + r0 + 4]);
      const float4 bb = *reinterpret_cast<const float4*>(&sE[d * 132 + tx4]);
      const float av[8] = {a0.x, a0.y, a0.z, a0.w, a1.x, a1.y, a1.z, a1.w};
      const float bv[4] = {bb.x, bb.y, bb.z, bb.w};
#pragma unroll
      for (int i = 0; i < 8; ++i)
#pragma unroll
        for (int j = 0; j < 4; ++j) acc[i][j] = fmaf(av[i], bv[j], acc[i][j]);
    }
#pragma unroll
    for (int j = 0; j < 4; ++j) {
      const float Ec = sEn[tx4 + j];
      const int c = c0 + tx4 + j;
#pragma unroll
      for (int i = 0; i < 8; ++i) {
        const float t1 = __fadd_rn(nl[i], Ec);
        const float s = __fsub_rn(t1, __fmul_rn(2.0f, acc[i][j]));
        if (s < v1[i]) { v1[i] = s; i1[i] = c; }
      }
    }
    // spread one_hot zeros for this chunk (64 rows x 32 float4-cols)
    const float4 z = make_float4(0.f, 0.f, 0.f, 0.f);
    for (int v = t; v < 2048; v += TPB) {
      const int r = v >> 5, c4 = v & 31;
      *reinterpret_cast<float4*>(oh + (size_t)(m0 + r) * 8192 + c0 + 4 * c4) =
          z;
    }
  }

  // merge across the 32 col-group lanes (xor<=16 stays in each half-wave),
  // first-index ties
#pragma unroll
  for (int m = 16; m >= 1; m >>= 1) {
#pragma unroll
    for (int i = 0; i < 8; ++i) {
      const float ov = __shfl_xor(v1[i], m);
      const int oi = __shfl_xor(i1[i], m);
      if (ov < v1[i] || (ov == v1[i] && oi < i1[i])) {
        v1[i] = ov; i1[i] = oi;
      }
    }
  }
  if (tx == 0) {
    float ls = 0.f;
#pragma unroll
    for (int i = 0; i < 8; ++i) {
      ridx[r0 + i] = i1[i];
      inds[m0 + r0 + i] = i1[i];
      ls += v1[i];  // d_min == ||q-lat||^2
    }
    atomicAdd(&lacc, ls);
  }
  __syncthreads();
  if (t == 0) lossp[blockIdx.x] = lacc;

  // patch ones: same (r, c4-slot) owner thread that wrote the zero earlier
  // (same-thread same-address program order, no fence needed)
  for (int v = t; v < 2048; v += TPB) {
    const int r = v >> 5, c4 = v & 31;
    const int ind = ridx[r];
    const int g4 = ind >> 2;  // global float4 col
    if ((g4 & 31) == c4) {
      float4 o = make_float4(0.f, 0.f, 0.f, 0.f);
      reinterpret_cast<float*>(&o)[ind & 3] = 1.f;
      *reinterpret_cast<float4*>(oh + (size_t)(m0 + r) * 8192 + 4 * g4) = o;
    }
  }
}

// ========================= fused decoder (32 rows) =========================
__global__ __launch_bounds__(TPB) void dec_fused(
    const float* __restrict__ emb, const int* __restrict__ inds,
    const float* __restrict__ WT1, const float* __restrict__ b1,
    const float* __restrict__ WT2, const float* __restrict__ b2,
    const float* __restrict__ WTmu, const float* __restrict__ bmu,
    const float* __restrict__ WTlv, const float* __restrict__ blv,
    float* __restrict__ xh, float* __restrict__ xv) {
  __shared__ float sQ[64 * 36];
  __shared__ float sG1[128 * 36];
  __shared__ float sG2[256 * 36];
  const int t = threadIdx.x;
  const int tx4 = (t & 15) * 4, ty2 = (t >> 4) * 2;
  const int m0 = blockIdx.x * 32;

  for (int v = t; v < 512; v += TPB) {  // gather q transposed
    const int k4 = v & 15, r = v >> 4;
    const int id = inds[m0 + r];
    const float4 e =
        *reinterpret_cast<const float4*>(emb + (size_t)id * 64 + 4 * k4);
    float* dst = &sQ[(4 * k4) * 36 + r];
    dst[0] = e.x; dst[36] = e.y; dst[72] = e.z; dst[108] = e.w;
  }
  __syncthreads();

  // L1: K=64, N=128 (acc[2][8])
  {
    float acc[2][8] = {};
#pragma unroll 8
    for (int k = 0; k < 64; ++k) {
      const float2 a = *reinterpret_cast<const float2*>(&sQ[k * 36 + ty2]);
      const float* wr = WT1 + (size_t)k * 128;
      const float4 b0 = *reinterpret_cast<const float4*>(wr + tx4);
      const float4 b1v = *reinterpret_cast<const float4*>(wr + 64 + tx4);
      const float av[2] = {a.x, a.y};
      const float bv[8] = {b0.x, b0.y, b0.z, b0.w, b1v.x, b1v.y, b1v.z, b1v.w};
#pragma unroll
      for (int i = 0; i < 2; ++i)
#pragma unroll
        for (int j = 0; j < 8; ++j) acc[i][j] = fmaf(av[i], bv[j], acc[i][j]);
    }
#pragma unroll
    for (int j = 0; j < 8; ++j) {
      const int col = (j >> 2) * 64 + tx4 + (j & 3);
      const float bj = b1[col];
#pragma unroll
      for (int i = 0; i < 2; ++i) {
        const float h = acc[i][j] + bj;
        sG1[col * 36 + ty2 + i] = h > 0.f ? h : 0.f;
      }
    }
  }
  __syncthreads();

  // L2: K=128, N=256 -> two passes (acc[2][8])
  for (int cp = 0; cp < 2; ++cp) {
    float acc[2][8] = {};
#pragma unroll 8
    for (int k = 0; k < 128; ++k) {
      const float2 a = *reinterpret_cast<const float2*>(&sG1[k * 36 + ty2]);
      const float* wr = WT2 + (size_t)k * 256 + cp * 128;
      const float4 b0 = *reinterpret_cast<const float4*>(wr + tx4);
      const float4 b1v = *reinterpret_cast<const float4*>(wr + 64 + tx4);
      const float av[2] = {a.x, a.y};
      const float bv[8] = {b0.x, b0.y, b0.z, b0.w, b1v.x, b1v.y, b1v.z, b1v.w};
#pragma unroll
      for (int i = 0; i < 2; ++i)
#pragma unroll
        for (int j = 0; j < 8; ++j) acc[i][j] = fmaf(av[i], bv[j], acc[i][j]);
    }
#pragma unroll
    for (int j = 0; j < 8; ++j) {
      const int col = cp * 128 + (j >> 2) * 64 + tx4 + (j & 3);
      const float bj = b2[col];
#pragma unroll
      for (int i = 0; i < 2; ++i) {
        const float h = acc[i][j] + bj;
        sG2[col * 36 + ty2 + i] = h > 0.f ? h : 0.f;
      }
    }
  }
  __syncthreads();

  // heads: K=256, N=128 each (acc[2][8])
  for (int head = 0; head < 2; ++head) {
    const float* WT = head ? WTlv : WTmu;
    const float* bb_ = head ? blv : bmu;
    float* o = head ? xv : xh;
    float acc[2][8] = {};
#pragma unroll 8
    for (int k = 0; k < 256; ++k) {
      const float2 a = *reinterpret_cast<const float2*>(&sG2[k * 36 + ty2]);
      const float* wr = WT + (size_t)k * 128;
      const float4 b0 = *reinterpret_cast<const float4*>(wr + tx4);
      const float4 b1v = *reinterpret_cast<const float4*>(wr + 64 + tx4);
      const float av[2] = {a.x, a.y};
      const float bv[8] = {b0.x, b0.y, b0.z, b0.w, b1v.x, b1v.y, b1v.z, b1v.w};
#pragma unroll
      for (int i = 0; i < 2; ++i)
#pragma unroll
        for (int j = 0; j < 8; ++j) acc[i][j] = fmaf(av[i], bv[j], acc[i][j]);
    }
#pragma unroll
    for (int i = 0; i < 2; ++i) {
      float4 o0, o1;
      o0.x = acc[i][0] + bb_[tx4 + 0];
      o0.y = acc[i][1] + bb_[tx4 + 1];
      o0.z = acc[i][2] + bb_[tx4 + 2];
      o0.w = acc[i][3] + bb_[tx4 + 3];
      o1.x = acc[i][4] + bb_[64 + tx4 + 0];
      o1.y = acc[i][5] + bb_[64 + tx4 + 1];
      o1.z = acc[i][6] + bb_[64 + tx4 + 2];
      o1.w = acc[i][7] + bb_[64 + tx4 + 3];
      float* orow = o + (size_t)(m0 + ty2 + i) * 128;
      *reinterpret_cast<float4*>(orow + tx4) = o0;
      *reinterpret_cast<float4*>(orow + 64 + tx4) = o1;
    }
  }
}

// vq_loss = 2.25 * sum(d_min) / (N*LAT)
__global__ void fin_kernel(const float* __restrict__ lossp,
                           float* __restrict__ outp) {
  const int t = threadIdx.x;  // 64
  double s = 0.0;
  for (int i = t; i < 512; i += 64) s += (double)lossp[i];
#pragma unroll
  for (int m = 32; m >= 1; m >>= 1) s += __shfl_xor(s, m);
  if (t == 0) *outp = (float)(2.25 * s / (32768.0 * 64.0));
}

// ---------------------------------------------------------------------------
extern "C" void kernel_launch(void* const* d_in, const int* in_sizes, int n_in,
                              void* d_out, int out_size, void* d_ws,
                              size_t ws_size, hipStream_t stream) {
  const float* x = (const float*)d_in[0];
  const float* eW1 = (const float*)d_in[1];
  const float* eb1 = (const float*)d_in[2];
  const float* eW2 = (const float*)d_in[3];
  const float* eb2 = (const float*)d_in[4];
  const float* eW3 = (const float*)d_in[5];
  const float* eb3 = (const float*)d_in[6];
  const float* emb = (const float*)d_in[7];
  const float* dW1 = (const float*)d_in[8];
  const float* db1 = (const float*)d_in[9];
  const float* dW2 = (const float*)d_in[10];
  const float* db2 = (const float*)d_in[11];
  const float* dWmu = (const float*)d_in[12];
  const float* dbmu = (const float*)d_in[13];
  const float* dWlv = (const float*)d_in[14];
  const float* dblv = (const float*)d_in[15];

  float* out = (float*)d_out;
  float* xhat = out;                 // [32768,128]
  float* xvar = out + 4194304;       // [32768,128]
  float* oh = out + 8388608;         // [32768,8192]
  float* lossout = out + 276824064;  // scalar

  // ws layout (floats)
  float* lat = (float*)d_ws;             // 2,097,152
  float* En = lat + 2097152;             // 8,192
  float* lossp = En + 8192;              // 512
  int* inds = (int*)(lossp + 512);       // 32,768
  float* embT = (float*)(inds + 32768);  // 524,288  [64][8192]
  float* wt = embT + 524288;             // WT pool
  float* wt1 = wt;                       // [128][256]
  float* wt2 = wt + 32768;               // [256][128]
  float* wt3 = wt + 65536;               // [128][64]
  float* uwt1 = wt + 73728;              // [64][128]
  float* uwt2 = wt + 81920;              // [128][256]
  float* uwtmu = wt + 114688;            // [256][128]
  float* uwtlv = wt + 147456;            // [256][128]

  wt_kernel<<<44, TPB, 0, stream>>>(eW1, eW2, eW3, dW1, dW2, dWmu, dWlv, wt);
  embt_kernel<<<128, TPB, 0, stream>>>(emb, embT, En);
  enc_fused<<<1024, TPB, 0, stream>>>(x, wt1, wt2, wt3, eb1, eb2, eb3, lat);
  vq_kernel<<<512, TPB, 0, stream>>>(lat, embT, En, inds, lossp, oh);
  dec_fused<<<1024, TPB, 0, stream>>>(emb, inds, uwt1, db1, uwt2, db2, uwtmu,
                                      dbmu, uwtlv, dblv, xhat, xvar);
  fin_kernel<<<1, 64, 0, stream>>>(lossp, lossout);
}

// Round 7
// 1699.892 us; speedup vs baseline: 1.4264x; 1.0687x over previous
//
#include <hip/hip_runtime.h>
#include <cfloat>
#include <climits>

#define TPB 256

// ---------------------------------------------------------------------------
// Numerics contract (rounds 3-6 PASSED): every matmul output is a
// k-sequential single-accumulator fp32 fmaf chain (k ascending), bias via
// __fadd_rn (encoder), norms via numpy pairwise order,
// d = fl(fl(nl+ne) - fl(2*dot)), argmin strict-< with first-index ties.
// Round-7: TPB=512 everywhere; vq 16x32 map acc[4][4] -> 24 waves/CU (75%);
// enc/dec 64 rows/block acc[4][8]/acc[4][4] -> 2x FMA per global load and
// 8 waves/CU. Chains unchanged -> outputs bit-identical.
// ---------------------------------------------------------------------------

// ============================ prep: W -> WT ================================
__global__ __launch_bounds__(TPB) void wt_kernel(
    const float* __restrict__ W1, const float* __restrict__ W2,
    const float* __restrict__ W3, const float* __restrict__ U1,
    const float* __restrict__ U2, const float* __restrict__ Umu,
    const float* __restrict__ Ulv, float* __restrict__ wt) {
  __shared__ float sB[64 * 68];
  const int b = blockIdx.x;
  const float* src; int R, C, lt; float* dst;
  if (b < 8)       { src = W1;  R = 256; C = 128; dst = wt;          lt = b; }
  else if (b < 16) { src = W2;  R = 128; C = 256; dst = wt + 32768;  lt = b - 8; }
  else if (b < 18) { src = W3;  R = 64;  C = 128; dst = wt + 65536;  lt = b - 16; }
  else if (b < 20) { src = U1;  R = 128; C = 64;  dst = wt + 73728;  lt = b - 18; }
  else if (b < 28) { src = U2;  R = 256; C = 128; dst = wt + 81920;  lt = b - 20; }
  else if (b < 36) { src = Umu; R = 128; C = 256; dst = wt + 114688; lt = b - 28; }
  else             { src = Ulv; R = 128; C = 256; dst = wt + 147456; lt = b - 36; }
  const int tiles_r = R >> 6;
  const int r0 = (lt % tiles_r) << 6, c0 = (lt / tiles_r) << 6;
  const int t = threadIdx.x;
  for (int v = t; v < 1024; v += TPB) {
    const int c4 = v & 15, r = v >> 4;
    const float4 w =
        *reinterpret_cast<const float4*>(src + (size_t)(r0 + r) * C + c0 + 4 * c4);
    *reinterpret_cast<float4*>(&sB[r * 68 + 4 * c4]) = w;
  }
  __syncthreads();
  for (int v = t; v < 1024; v += TPB) {
    const int r4 = v & 15, c = v >> 4;
    float4 o;
    o.x = sB[(4 * r4 + 0) * 68 + c];
    o.y = sB[(4 * r4 + 1) * 68 + c];
    o.z = sB[(4 * r4 + 2) * 68 + c];
    o.w = sB[(4 * r4 + 3) * 68 + c];
    *reinterpret_cast<float4*>(dst + (size_t)(c0 + c) * R + r0 + 4 * r4) = o;
  }
}

// ====================== prep: emb -> embT, + En ============================
__global__ __launch_bounds__(TPB) void embt_kernel(const float* __restrict__ emb,
                                                   float* __restrict__ embT,
                                                   float* __restrict__ En) {
  __shared__ float sB[64 * 68];  // [code][d]
  const int c0 = blockIdx.x * 64;
  const int t = threadIdx.x;
  for (int v = t; v < 1024; v += TPB) {
    const int d4 = v & 15, r = v >> 4;
    const float4 e =
        *reinterpret_cast<const float4*>(emb + (size_t)(c0 + r) * 64 + 4 * d4);
    *reinterpret_cast<float4*>(&sB[r * 68 + 4 * d4]) = e;
  }
  __syncthreads();
  if (t < 64) {  // numpy pairwise ||e||^2
    const float* row = &sB[t * 68];
    float q[8];
#pragma unroll
    for (int j = 0; j < 8; ++j) q[j] = __fmul_rn(row[j], row[j]);
#pragma unroll
    for (int m = 1; m < 8; ++m)
#pragma unroll
      for (int j = 0; j < 8; ++j) {
        const float v = row[m * 8 + j];
        q[j] = __fadd_rn(q[j], __fmul_rn(v, v));
      }
    En[c0 + t] = __fadd_rn(
        __fadd_rn(__fadd_rn(q[0], q[1]), __fadd_rn(q[2], q[3])),
        __fadd_rn(__fadd_rn(q[4], q[5]), __fadd_rn(q[6], q[7])));
  }
  for (int v = t; v < 1024; v += TPB) {
    const int r4 = v & 15, d = v >> 4;
    float4 o;
    o.x = sB[(4 * r4 + 0) * 68 + d];
    o.y = sB[(4 * r4 + 1) * 68 + d];
    o.z = sB[(4 * r4 + 2) * 68 + d];
    o.w = sB[(4 * r4 + 3) * 68 + d];
    *reinterpret_cast<float4*>(embT + (size_t)d * 8192 + c0 + 4 * r4) = o;
  }
}

// ========================= fused encoder (64 rows, 512 thr) ================
// Activations LDS-resident transposed [k][68]; weights streamed from WT in
// L2. acc[4][8] (L1): 32 FMA per 2 global float4 loads. 139 KB LDS, 8 waves.
__global__ __launch_bounds__(512) void enc_fused(
    const float* __restrict__ x, const float* __restrict__ WT1,
    const float* __restrict__ WT2, const float* __restrict__ WT3,
    const float* __restrict__ b1, const float* __restrict__ b2,
    const float* __restrict__ b3, float* __restrict__ lat) {
  __shared__ float sX[128 * 68];
  __shared__ float sH1[256 * 68];
  __shared__ float sH2[128 * 68];
  const int t = threadIdx.x;
  const int m0 = blockIdx.x * 64;

  for (int v = t; v < 2048; v += 512) {  // stage x transposed
    const int k4 = v & 31, r = v >> 5;
    const float4 xv =
        *reinterpret_cast<const float4*>(x + (size_t)(m0 + r) * 128 + 4 * k4);
    float* dst = &sX[(4 * k4) * 68 + r];
    dst[0] = xv.x; dst[68] = xv.y; dst[136] = xv.z; dst[204] = xv.w;
  }
  __syncthreads();

  // L1: K=128, N=256. 32 colgroups (8 cols) x 16 rowgroups (4 rows)
  {
    const int cg8 = (t & 31) * 8, rg4 = (t >> 5) * 4;
    float acc[4][8] = {};
#pragma unroll 8
    for (int k = 0; k < 128; ++k) {
      const float4 a = *reinterpret_cast<const float4*>(&sX[k * 68 + rg4]);
      const float* wr = WT1 + (size_t)k * 256 + cg8;
      const float4 b0 = *reinterpret_cast<const float4*>(wr);
      const float4 b1v = *reinterpret_cast<const float4*>(wr + 4);
      const float av[4] = {a.x, a.y, a.z, a.w};
      const float bv[8] = {b0.x, b0.y, b0.z, b0.w, b1v.x, b1v.y, b1v.z, b1v.w};
#pragma unroll
      for (int i = 0; i < 4; ++i)
#pragma unroll
        for (int j = 0; j < 8; ++j) acc[i][j] = fmaf(av[i], bv[j], acc[i][j]);
    }
#pragma unroll
    for (int j = 0; j < 8; ++j) {
      const int col = cg8 + j;
      const float bj = b1[col];
#pragma unroll
      for (int i = 0; i < 4; ++i) {
        const float h = __fadd_rn(acc[i][j], bj);
        sH1[col * 68 + rg4 + i] = h > 0.f ? h : 0.f;
      }
    }
  }
  __syncthreads();

  // L2: K=256, N=128. 32 colgroups (4 cols) x 16 rowgroups (4 rows)
  {
    const int cg4 = (t & 31) * 4, rg4 = (t >> 5) * 4;
    float acc[4][4] = {};
#pragma unroll 8
    for (int k = 0; k < 256; ++k) {
      const float4 a = *reinterpret_cast<const float4*>(&sH1[k * 68 + rg4]);
      const float4 bb =
          *reinterpret_cast<const float4*>(WT2 + (size_t)k * 128 + cg4);
      const float av[4] = {a.x, a.y, a.z, a.w};
      const float bv[4] = {bb.x, bb.y, bb.z, bb.w};
#pragma unroll
      for (int i = 0; i < 4; ++i)
#pragma unroll
        for (int j = 0; j < 4; ++j) acc[i][j] = fmaf(av[i], bv[j], acc[i][j]);
    }
#pragma unroll
    for (int j = 0; j < 4; ++j) {
      const int col = cg4 + j;
      const float bj = b2[col];
#pragma unroll
      for (int i = 0; i < 4; ++i) {
        const float h = __fadd_rn(acc[i][j], bj);
        sH2[col * 68 + rg4 + i] = h > 0.f ? h : 0.f;
      }
    }
  }
  __syncthreads();

  // L3: K=128, N=64. 16 colgroups (4 cols) x 32 rowgroups (2 rows) -> lat
  {
    const int cg4 = (t & 15) * 4, rg2 = (t >> 4) * 2;
    float acc[2][4] = {};
#pragma unroll 8
    for (int k = 0; k < 128; ++k) {
      const float2 a = *reinterpret_cast<const float2*>(&sH2[k * 68 + rg2]);
      const float4 bb =
          *reinterpret_cast<const float4*>(WT3 + (size_t)k * 64 + cg4);
      const float av[2] = {a.x, a.y};
      const float bv[4] = {bb.x, bb.y, bb.z, bb.w};
#pragma unroll
      for (int i = 0; i < 2; ++i)
#pragma unroll
        for (int j = 0; j < 4; ++j) acc[i][j] = fmaf(av[i], bv[j], acc[i][j]);
    }
#pragma unroll
    for (int i = 0; i < 2; ++i) {
      float4 o;
      o.x = __fadd_rn(acc[i][0], b3[cg4 + 0]);
      o.y = __fadd_rn(acc[i][1], b3[cg4 + 1]);
      o.z = __fadd_rn(acc[i][2], b3[cg4 + 2]);
      o.w = __fadd_rn(acc[i][3], b3[cg4 + 3]);
      *reinterpret_cast<float4*>(lat + (size_t)(m0 + rg2 + i) * 64 + cg4) = o;
    }
  }
}

// ================================ VQ (512 thr) =============================
// 64 rows/block, 128-col LDS-staged chunks. 16 rowgroups (4 rows) x 32
// colgroups (4 cols); acc[4][4]: per d = 1 broadcast b128 A + 1 2-way b128 B
// per 16 FMAs. LDS 51.6 KB -> 3 blocks x 8 waves = 24 waves/CU.
__global__ __launch_bounds__(512, 6) void vq_kernel(
    const float* __restrict__ lat, const float* __restrict__ embT,
    const float* __restrict__ En, int* __restrict__ inds,
    float* __restrict__ lossp, float* __restrict__ oh) {
  __shared__ float sL[64 * 68];   // lat_t [64d][68r]
  __shared__ float sE[64 * 132];  // emb_t chunk [64d][132c]
  __shared__ float sEn[128];
  __shared__ float snl[64];
  __shared__ int ridx[64];
  __shared__ float lacc;
  const int t = threadIdx.x;
  const int tx = t & 31, ty = t >> 5;  // colgroup (4 cols), rowgroup (4 rows)
  const int r0 = ty * 4;
  const int tx4 = tx * 4;
  const int m0 = blockIdx.x * 64;

  for (int v = t; v < 1024; v += 512) {
    const int r = v >> 4, d4 = v & 15;
    const float4 lv =
        *reinterpret_cast<const float4*>(lat + (size_t)(m0 + r) * 64 + 4 * d4);
    float* dst = &sL[(4 * d4) * 68 + r];
    dst[0] = lv.x; dst[68] = lv.y; dst[136] = lv.z; dst[204] = lv.w;
  }
  if (t == 0) lacc = 0.f;
  __syncthreads();
  if (t < 64) {  // numpy pairwise ||lat_r||^2
    float q[8];
#pragma unroll
    for (int j = 0; j < 8; ++j) {
      const float v = sL[j * 68 + t];
      q[j] = __fmul_rn(v, v);
    }
#pragma unroll
    for (int m = 1; m < 8; ++m)
#pragma unroll
      for (int j = 0; j < 8; ++j) {
        const float v = sL[(m * 8 + j) * 68 + t];
        q[j] = __fadd_rn(q[j], __fmul_rn(v, v));
      }
    snl[t] = __fadd_rn(
        __fadd_rn(__fadd_rn(q[0], q[1]), __fadd_rn(q[2], q[3])),
        __fadd_rn(__fadd_rn(q[4], q[5]), __fadd_rn(q[6], q[7])));
  }
  __syncthreads();
  float nl[4];
#pragma unroll
  for (int i = 0; i < 4; ++i) nl[i] = snl[r0 + i];

  float v1[4];
  int i1[4];
#pragma unroll
  for (int i = 0; i < 4; ++i) { v1[i] = FLT_MAX; i1[i] = INT_MAX; }

  for (int ch = 0; ch < 64; ++ch) {  // 8192 codes, 128-col chunks
    const int c0 = ch * 128;
    __syncthreads();
    for (int v = t; v < 2048; v += 512) {  // stage sE: coalesced, conflict-free
      const int cl = v & 31, d = v >> 5;
      const float4 e = *reinterpret_cast<const float4*>(
          embT + (size_t)d * 8192 + c0 + 4 * cl);
      *reinterpret_cast<float4*>(&sE[d * 132 + 4 * cl]) = e;
    }
    if (t < 128) sEn[t] = En[c0 + t];
    __syncthreads();

    float acc[4][4] = {};
#pragma unroll 4
    for (int d = 0; d < 64; ++d) {  // k-sequential fma chain
      const float4 a = *reinterpret_cast<const float4*>(&sL[d * 68 + r0]);
      const float4 bb = *reinterpret_cast<const float4*>(&sE[d * 132 + tx4]);
      const float av[4] = {a.x, a.y, a.z, a.w};
      const float bv[4] = {bb.x, bb.y, bb.z, bb.w};
#pragma unroll
      for (int i = 0; i < 4; ++i)
#pragma unroll
        for (int j = 0; j < 4; ++j) acc[i][j] = fmaf(av[i], bv[j], acc[i][j]);
    }
#pragma unroll
    for (int j = 0; j < 4; ++j) {
      const float Ec = sEn[tx4 + j];
      const int c = c0 + tx4 + j;
#pragma unroll
      for (int i = 0; i < 4; ++i) {
        const float t1 = __fadd_rn(nl[i], Ec);
        const float s = __fsub_rn(t1, __fmul_rn(2.0f, acc[i][j]));
        if (s < v1[i]) { v1[i] = s; i1[i] = c; }
      }
    }
    // spread one_hot zeros for this chunk (64 rows x 32 float4-cols)
    const float4 z = make_float4(0.f, 0.f, 0.f, 0.f);
    for (int v = t; v < 2048; v += 512) {
      const int r = v >> 5, c4 = v & 31;
      *reinterpret_cast<float4*>(oh + (size_t)(m0 + r) * 8192 + c0 + 4 * c4) =
          z;
    }
  }

  // merge across the 32 col-group lanes (xor<=16 stays in each 32-lane half;
  // both halves of a wave share ty pairs -> rows preserved), first-index ties
#pragma unroll
  for (int m = 16; m >= 1; m >>= 1) {
#pragma unroll
    for (int i = 0; i < 4; ++i) {
      const float ov = __shfl_xor(v1[i], m);
      const int oi = __shfl_xor(i1[i], m);
      if (ov < v1[i] || (ov == v1[i] && oi < i1[i])) {
        v1[i] = ov; i1[i] = oi;
      }
    }
  }
  if (tx == 0) {
    float ls = 0.f;
#pragma unroll
    for (int i = 0; i < 4; ++i) {
      ridx[r0 + i] = i1[i];
      inds[m0 + r0 + i] = i1[i];
      ls += v1[i];  // d_min == ||q-lat||^2
    }
    atomicAdd(&lacc, ls);
  }
  __syncthreads();
  if (t == 0) lossp[blockIdx.x] = lacc;

  // patch ones: same (r, c4-slot) owner thread that wrote the zero earlier
  // (same-thread same-address program order, no fence needed)
  for (int v = t; v < 2048; v += 512) {
    const int r = v >> 5, c4 = v & 31;
    const int ind = ridx[r];
    const int g4 = ind >> 2;  // global float4 col
    if ((g4 & 31) == c4) {
      float4 o = make_float4(0.f, 0.f, 0.f, 0.f);
      reinterpret_cast<float*>(&o)[ind & 3] = 1.f;
      *reinterpret_cast<float4*>(oh + (size_t)(m0 + r) * 8192 + 4 * g4) = o;
    }
  }
}

// ===================== fused decoder (64 rows, 512 thr) ====================
__global__ __launch_bounds__(512) void dec_fused(
    const float* __restrict__ emb, const int* __restrict__ inds,
    const float* __restrict__ WT1, const float* __restrict__ b1,
    const float* __restrict__ WT2, const float* __restrict__ b2,
    const float* __restrict__ WTmu, const float* __restrict__ bmu,
    const float* __restrict__ WTlv, const float* __restrict__ blv,
    float* __restrict__ xh, float* __restrict__ xv) {
  __shared__ float sQ[64 * 68];
  __shared__ float sG1[128 * 68];
  __shared__ float sG2[256 * 68];
  const int t = threadIdx.x;
  const int m0 = blockIdx.x * 64;

  for (int v = t; v < 1024; v += 512) {  // gather q transposed
    const int k4 = v & 15, r = v >> 4;
    const int id = inds[m0 + r];
    const float4 e =
        *reinterpret_cast<const float4*>(emb + (size_t)id * 64 + 4 * k4);
    float* dst = &sQ[(4 * k4) * 68 + r];
    dst[0] = e.x; dst[68] = e.y; dst[136] = e.z; dst[204] = e.w;
  }
  __syncthreads();

  // L1: K=64, N=128. 32 colgroups (4) x 16 rowgroups (4)
  {
    const int cg4 = (t & 31) * 4, rg4 = (t >> 5) * 4;
    float acc[4][4] = {};
#pragma unroll 8
    for (int k = 0; k < 64; ++k) {
      const float4 a = *reinterpret_cast<const float4*>(&sQ[k * 68 + rg4]);
      const float4 bb =
          *reinterpret_cast<const float4*>(WT1 + (size_t)k * 128 + cg4);
      const float av[4] = {a.x, a.y, a.z, a.w};
      const float bv[4] = {bb.x, bb.y, bb.z, bb.w};
#pragma unroll
      for (int i = 0; i < 4; ++i)
#pragma unroll
        for (int j = 0; j < 4; ++j) acc[i][j] = fmaf(av[i], bv[j], acc[i][j]);
    }
#pragma unroll
    for (int j = 0; j < 4; ++j) {
      const int col = cg4 + j;
      const float bj = b1[col];
#pragma unroll
      for (int i = 0; i < 4; ++i) {
        const float h = acc[i][j] + bj;
        sG1[col * 68 + rg4 + i] = h > 0.f ? h : 0.f;
      }
    }
  }
  __syncthreads();

  // L2: K=128, N=256. 32 colgroups (8) x 16 rowgroups (4)
  {
    const int cg8 = (t & 31) * 8, rg4 = (t >> 5) * 4;
    float acc[4][8] = {};
#pragma unroll 8
    for (int k = 0; k < 128; ++k) {
      const float4 a = *reinterpret_cast<const float4*>(&sG1[k * 68 + rg4]);
      const float* wr = WT2 + (size_t)k * 256 + cg8;
      const float4 b0 = *reinterpret_cast<const float4*>(wr);
      const float4 b1v = *reinterpret_cast<const float4*>(wr + 4);
      const float av[4] = {a.x, a.y, a.z, a.w};
      const float bv[8] = {b0.x, b0.y, b0.z, b0.w, b1v.x, b1v.y, b1v.z, b1v.w};
#pragma unroll
      for (int i = 0; i < 4; ++i)
#pragma unroll
        for (int j = 0; j < 8; ++j) acc[i][j] = fmaf(av[i], bv[j], acc[i][j]);
    }
#pragma unroll
    for (int j = 0; j < 8; ++j) {
      const int col = cg8 + j;
      const float bj = b2[col];
#pragma unroll
      for (int i = 0; i < 4; ++i) {
        const float h = acc[i][j] + bj;
        sG2[col * 68 + rg4 + i] = h > 0.f ? h : 0.f;
      }
    }
  }
  __syncthreads();

  // heads: K=256, N=128 each. 32 colgroups (4) x 16 rowgroups (4)
  for (int head = 0; head < 2; ++head) {
    const float* WT = head ? WTlv : WTmu;
    const float* bb_ = head ? blv : bmu;
    float* o = head ? xv : xh;
    const int cg4 = (t & 31) * 4, rg4 = (t >> 5) * 4;
    float acc[4][4] = {};
#pragma unroll 8
    for (int k = 0; k < 256; ++k) {
      const float4 a = *reinterpret_cast<const float4*>(&sG2[k * 68 + rg4]);
      const float4 bb =
          *reinterpret_cast<const float4*>(WT + (size_t)k * 128 + cg4);
      const float av[4] = {a.x, a.y, a.z, a.w};
      const float bv[4] = {bb.x, bb.y, bb.z, bb.w};
#pragma unroll
      for (int i = 0; i < 4; ++i)
#pragma unroll
        for (int j = 0; j < 4; ++j) acc[i][j] = fmaf(av[i], bv[j], acc[i][j]);
    }
#pragma unroll
    for (int i = 0; i < 4; ++i) {
      float4 ov;
      ov.x = acc[i][0] + bb_[cg4 + 0];
      ov.y = acc[i][1] + bb_[cg4 + 1];
      ov.z = acc[i][2] + bb_[cg4 + 2];
      ov.w = acc[i][3] + bb_[cg4 + 3];
      *reinterpret_cast<float4*>(o + (size_t)(m0 + rg4 + i) * 128 + cg4) = ov;
    }
  }
}

// vq_loss = 2.25 * sum(d_min) / (N*LAT)
__global__ void fin_kernel(const float* __restrict__ lossp,
                           float* __restrict__ outp) {
  const int t = threadIdx.x;  // 64
  double s = 0.0;
  for (int i = t; i < 512; i += 64) s += (double)lossp[i];
#pragma unroll
  for (int m = 32; m >= 1; m >>= 1) s += __shfl_xor(s, m);
  if (t == 0) *outp = (float)(2.25 * s / (32768.0 * 64.0));
}

// ---------------------------------------------------------------------------
extern "C" void kernel_launch(void* const* d_in, const int* in_sizes, int n_in,
                              void* d_out, int out_size, void* d_ws,
                              size_t ws_size, hipStream_t stream) {
  const float* x = (const float*)d_in[0];
  const float* eW1 = (const float*)d_in[1];
  const float* eb1 = (const float*)d_in[2];
  const float* eW2 = (const float*)d_in[3];
  const float* eb2 = (const float*)d_in[4];
  const float* eW3 = (const float*)d_in[5];
  const float* eb3 = (const float*)d_in[6];
  const float* emb = (const float*)d_in[7];
  const float* dW1 = (const float*)d_in[8];
  const float* db1 = (const float*)d_in[9];
  const float* dW2 = (const float*)d_in[10];
  const float* db2 = (const float*)d_in[11];
  const float* dWmu = (const float*)d_in[12];
  const float* dbmu = (const float*)d_in[13];
  const float* dWlv = (const float*)d_in[14];
  const float* dblv = (const float*)d_in[15];

  float* out = (float*)d_out;
  float* xhat = out;                 // [32768,128]
  float* xvar = out + 4194304;       // [32768,128]
  float* oh = out + 8388608;         // [32768,8192]
  float* lossout = out + 276824064;  // scalar

  // ws layout (floats)
  float* lat = (float*)d_ws;             // 2,097,152
  float* En = lat + 2097152;             // 8,192
  float* lossp = En + 8192;              // 512
  int* inds = (int*)(lossp + 512);       // 32,768
  float* embT = (float*)(inds + 32768);  // 524,288  [64][8192]
  float* wt = embT + 524288;             // WT pool
  float* wt1 = wt;                       // [128][256]
  float* wt2 = wt + 32768;               // [256][128]
  float* wt3 = wt + 65536;               // [128][64]
  float* uwt1 = wt + 73728;              // [64][128]
  float* uwt2 = wt + 81920;              // [128][256]
  float* uwtmu = wt + 114688;            // [256][128]
  float* uwtlv = wt + 147456;            // [256][128]

  wt_kernel<<<44, TPB, 0, stream>>>(eW1, eW2, eW3, dW1, dW2, dWmu, dWlv, wt);
  embt_kernel<<<128, TPB, 0, stream>>>(emb, embT, En);
  enc_fused<<<512, 512, 0, stream>>>(x, wt1, wt2, wt3, eb1, eb2, eb3, lat);
  vq_kernel<<<512, 512, 0, stream>>>(lat, embT, En, inds, lossp, oh);
  dec_fused<<<512, 512, 0, stream>>>(emb, inds, uwt1, db1, uwt2, db2, uwtmu,
                                     dbmu, uwtlv, dblv, xhat, xvar);
  fin_kernel<<<1, 64, 0, stream>>>(lossp, lossout);
}